// Round 13
// baseline (7049.314 us; speedup 1.0000x reference)
//
#include <hip/hip_runtime.h>
#include <math.h>

// Sinkhorn OT layer, B=8192, C=256, L=100, LAMBD=1.
//
// U = log_u - ||x_i||^2, V = log_v - ||y_j||^2, G[i][j] = 2*dot(x_i,y_j):
//   U[i] = -LSE_j(G[i][j] + V[j]),  V[j] = -LSE_i(G[i][j] + U[i])
// init V[j] = -||y_j||^2. Final: out[i] = y[argmax_j(G[i][j]+V[j])].
//
// R6 int24 G: 7498. R13 register-resident fused dense iter: 4875 (~43
// us/iter, at BW floor). R14 sparse: NUMERICS validated (absmax 0, tau=80,
// per-row tightening, ~24-iter re-extract) but slow mechanics. R16 CSR+CSC:
// CRASHED (unbounded nnz -> OOB). R17: fixed-stride KMAX=768, overflow
// impossible by construction -> INFRA FAILURE (container, no verdict).
// R18 = R17 resubmit + zero-cost hardening: every index loaded from
// workspace is masked on use (row/col ids & 8191, CSC slot min-clamped),
// so even corrupted memory cannot produce an OOB address.
//  - extract: per-row online LSE -> W; count-only tau-tightening passes
//    (80, -16 steps) until cnt<=KMAX; ONE bounded write pass + column
//    histogram. CSR slot = row*KMAX+pos, pos<KMAX guarded.
//  - CSC: histogram + 1-block prefix + scatter (cursor atomics).
//  - sparse_W: wave/row, butterfly max then sum-exp.
//  - sparse_colV: wave/column, V_j -= log(sum exp(val-W_i)); no atomics,
//    no pm, no combine; empty column -> V frozen (R14-validated).
// Schedule: 8 dense + 4 x (extract + 23 sparse) = 100 V-updates.
// ws: 192 (G) + 60 (CSR+CSC, aliases dense pm) = 252 MiB.

#define B 8192
#define C 256
#define RPB 16                     // rows per dense fused block
#define NCH (B / RPB)              // 512 dense chunks
#define KMAX 768                   // sparse entries per row (fixed stride)
#define NMAX (B * KMAX)            // 6291456 total capacity
#define TAU 80.0f

#define QS 65536.0f                // (2*acc) * 32768 == acc * 65536
#define QI 3.0517578125e-5f        // 2^-15

typedef float f32x4 __attribute__((ext_vector_type(4)));
typedef unsigned short u16x8 __attribute__((ext_vector_type(8)));
typedef signed char i8x16 __attribute__((ext_vector_type(16)));
typedef signed char i8x8 __attribute__((ext_vector_type(8)));

__device__ __align__(16) float g_V[B];
__device__ __align__(16) float g_W[B];
__device__ int g_rowcnt[B], g_colcnt[B], g_colofs[B];

// ---------------- init: V[j] = -||y_j||^2 ----------------
__global__ __launch_bounds__(256) void init_V(const float* __restrict__ y) {
    int wave = threadIdx.x >> 6;
    int lane = threadIdx.x & 63;
    int row = blockIdx.x * 4 + wave;
    const f32x4* yr = (const f32x4*)(y + (size_t)row * C);
    f32x4 v = yr[lane];
    float s = v.x * v.x + v.y * v.y + v.z * v.z + v.w * v.w;
    #pragma unroll
    for (int off = 32; off; off >>= 1) s += __shfl_down(s, off, 64);
    if (lane == 0) g_V[row] = -s;
}

// ---------------- GEMM: G = 2 * x @ y^T, quantized to int24 ----------------
#define GT 64
#define GKT 64
#define LSTR (GKT + 4)

__global__ __launch_bounds__(256) void gemm_G(const float* __restrict__ x,
                                              const float* __restrict__ y,
                                              unsigned short* __restrict__ Glo,
                                              signed char* __restrict__ Ghi) {
    __shared__ float As[GT][LSTR];
    __shared__ float Bs[GT][LSTR];
    int bi = blockIdx.y * GT;
    int bj = blockIdx.x * GT;
    int t = threadIdx.x;
    int tx = t & 15, ty = t >> 4;
    float acc[4][4] = {};
    for (int kk = 0; kk < C; kk += GKT) {
        #pragma unroll
        for (int l = 0; l < 4; ++l) {
            int idx = t + l * 256;
            int r = idx >> 4;
            int c4 = idx & 15;
            *(f32x4*)&As[r][c4 * 4] =
                *(const f32x4*)(x + (size_t)(bi + r) * C + kk + c4 * 4);
            *(f32x4*)&Bs[r][c4 * 4] =
                *(const f32x4*)(y + (size_t)(bj + r) * C + kk + c4 * 4);
        }
        __syncthreads();
        #pragma unroll
        for (int k4 = 0; k4 < GKT / 4; ++k4) {
            f32x4 a[4], b[4];
            #pragma unroll
            for (int ii = 0; ii < 4; ++ii)
                a[ii] = *(const f32x4*)&As[ty * 4 + ii][k4 * 4];
            #pragma unroll
            for (int jj = 0; jj < 4; ++jj)
                b[jj] = *(const f32x4*)&Bs[tx + 16 * jj][k4 * 4];
            #pragma unroll
            for (int ii = 0; ii < 4; ++ii)
                #pragma unroll
                for (int jj = 0; jj < 4; ++jj) {
                    acc[ii][jj] = fmaf(a[ii].x, b[jj].x, acc[ii][jj]);
                    acc[ii][jj] = fmaf(a[ii].y, b[jj].y, acc[ii][jj]);
                    acc[ii][jj] = fmaf(a[ii].z, b[jj].z, acc[ii][jj]);
                    acc[ii][jj] = fmaf(a[ii].w, b[jj].w, acc[ii][jj]);
                }
        }
        __syncthreads();
    }
    #pragma unroll
    for (int ii = 0; ii < 4; ++ii) {
        int gi = bi + ty * 4 + ii;
        #pragma unroll
        for (int jj = 0; jj < 4; ++jj) {
            size_t idx = (size_t)gi * B + bj + tx + 16 * jj;
            float gs = acc[ii][jj] * QS;
            gs = fminf(fmaxf(gs, -8388607.0f), 8388607.0f);
            int v = __float2int_rn(gs);
            Glo[idx] = (unsigned short)(v & 0xFFFF);
            Ghi[idx] = (signed char)(v >> 16);
        }
    }
}

// ---------------- dense fused row+col pass (R13, unchanged) ----------------
__global__ __launch_bounds__(512, 4) void fused_iter(
        const unsigned short* __restrict__ Glo,
        const signed char* __restrict__ Ghi,
        float* __restrict__ pm) {
    __shared__ float wm[2][2][8];
    __shared__ float ws[2][2][8];
    int t = threadIdx.x;
    int chunk = blockIdx.x;
    int i0 = chunk * RPB;
    int wave = t >> 6, lane = t & 63;

    float vreg[16];
    #pragma unroll
    for (int q = 0; q < 4; ++q) {
        f32x4 v = *(const f32x4*)&g_V[16 * t + 4 * q];
        vreg[4 * q + 0] = v.x; vreg[4 * q + 1] = v.y;
        vreg[4 * q + 2] = v.z; vreg[4 * q + 3] = v.w;
    }
    float cs[16];
    #pragma unroll
    for (int k = 0; k < 16; ++k) cs[k] = 0.0f;

    for (int w = 0; w < RPB / 2; ++w) {
        int buf = w & 1;
        int ra = i0 + 2 * w;
        int rb = ra + 1;
        float val0[16], val1[16];
        {
            const u16x8* lop = (const u16x8*)(Glo + (size_t)ra * B);
            const i8x16* hp  = (const i8x16*)(Ghi + (size_t)ra * B);
            u16x8 a0 = lop[2 * t], a1 = lop[2 * t + 1];
            i8x16 h = hp[t];
            #pragma unroll
            for (int e = 0; e < 8; ++e) {
                int q0 = ((int)h[e] << 16) | (int)a0[e];
                val0[e] = fmaf((float)q0, QI, vreg[e]);
                int q1 = ((int)h[8 + e] << 16) | (int)a1[e];
                val0[8 + e] = fmaf((float)q1, QI, vreg[8 + e]);
            }
        }
        {
            const u16x8* lop = (const u16x8*)(Glo + (size_t)rb * B);
            const i8x16* hp  = (const i8x16*)(Ghi + (size_t)rb * B);
            u16x8 a0 = lop[2 * t], a1 = lop[2 * t + 1];
            i8x16 h = hp[t];
            #pragma unroll
            for (int e = 0; e < 8; ++e) {
                int q0 = ((int)h[e] << 16) | (int)a0[e];
                val1[e] = fmaf((float)q0, QI, vreg[e]);
                int q1 = ((int)h[8 + e] << 16) | (int)a1[e];
                val1[8 + e] = fmaf((float)q1, QI, vreg[8 + e]);
            }
        }
        float M0 = val0[0], M1 = val1[0];
        #pragma unroll
        for (int k = 1; k < 16; ++k) {
            M0 = fmaxf(M0, val0[k]);
            M1 = fmaxf(M1, val1[k]);
        }
        #pragma unroll
        for (int off = 1; off < 64; off <<= 1) {
            M0 = fmaxf(M0, __shfl_xor(M0, off, 64));
            M1 = fmaxf(M1, __shfl_xor(M1, off, 64));
        }
        float s0 = 0.0f, s1 = 0.0f;
        #pragma unroll
        for (int k = 0; k < 16; ++k) {
            val0[k] = __expf(val0[k] - M0); s0 += val0[k];
            val1[k] = __expf(val1[k] - M1); s1 += val1[k];
        }
        #pragma unroll
        for (int off = 1; off < 64; off <<= 1) {
            s0 += __shfl_xor(s0, off, 64);
            s1 += __shfl_xor(s1, off, 64);
        }
        if (lane == 0) {
            wm[buf][0][wave] = M0; ws[buf][0][wave] = s0;
            wm[buf][1][wave] = M1; ws[buf][1][wave] = s1;
        }
        __syncthreads();
        float gM0 = wm[buf][0][0], gM1 = wm[buf][1][0];
        #pragma unroll
        for (int k = 1; k < 8; ++k) {
            gM0 = fmaxf(gM0, wm[buf][0][k]);
            gM1 = fmaxf(gM1, wm[buf][1][k]);
        }
        float gS0 = 0.0f, gS1 = 0.0f;
        #pragma unroll
        for (int k = 0; k < 8; ++k) {
            gS0 += ws[buf][0][k] * __expf(wm[buf][0][k] - gM0);
            gS1 += ws[buf][1][k] * __expf(wm[buf][1][k] - gM1);
        }
        float f0 = __expf(M0 - gM0) / gS0;
        float f1 = __expf(M1 - gM1) / gS1;
        #pragma unroll
        for (int k = 0; k < 16; ++k) {
            cs[k] = fmaf(val0[k], f0, cs[k]);
            cs[k] = fmaf(val1[k], f1, cs[k]);
        }
    }
    #pragma unroll
    for (int q = 0; q < 4; ++q) {
        f32x4 o = {cs[4 * q + 0], cs[4 * q + 1], cs[4 * q + 2], cs[4 * q + 3]};
        *(f32x4*)&pm[(size_t)chunk * B + 16 * t + 4 * q] = o;
    }
}

// ---------------- dense combine: V[j] -= log(colsum) ----------------
__global__ __launch_bounds__(256) void col_combine(const float* __restrict__ pm) {
    int t = threadIdx.x;
    int pl = t & 31;
    int g = t >> 5;
    int j = blockIdx.x * 32 + pl;
    float s = 0.0f;
    #pragma unroll 8
    for (int c = g * 64; c < g * 64 + 64; ++c)
        s += pm[(size_t)c * B + j];
    __shared__ float ls[8][32];
    ls[g][pl] = s;
    __syncthreads();
    if (t < 32) {
        float s0 = ls[0][t];
        #pragma unroll
        for (int gg = 1; gg < 8; ++gg) s0 += ls[gg][t];
        int jj = blockIdx.x * 32 + t;
        g_V[jj] -= logf(fmaxf(s0, 1e-30f));
    }
}

// ---------------- sparse machinery ----------------
__global__ __launch_bounds__(256) void sreset() {
    int i = blockIdx.x * 256 + threadIdx.x;
    g_colcnt[i] = 0;
}

// extract: wave per row. (1) online LSE -> W. (2) count-only passes with
// tau tightening until cnt <= KMAX. (3) one bounded write pass + histogram.
__global__ __launch_bounds__(512, 2) void extract(
        const unsigned short* __restrict__ Glo,
        const signed char* __restrict__ Ghi,
        unsigned short* __restrict__ cidx,
        unsigned short* __restrict__ clo,
        signed char* __restrict__ chi) {
    int t = threadIdx.x;
    int wave = t >> 6, lane = t & 63;
    int row = blockIdx.x * 8 + wave;
    const u16x8* lop = (const u16x8*)(Glo + (size_t)row * B);
    const i8x8*  hp  = (const i8x8*)(Ghi + (size_t)row * B);

    // (1) online (m,s) per lane, butterfly -> W
    float m = -1e30f, s = 0.0f;
    for (int c = 0; c < 16; ++c) {
        int vi = c * 64 + lane;
        u16x8 lo = lop[vi];
        i8x8  hi = hp[vi];
        #pragma unroll
        for (int e = 0; e < 8; ++e) {
            int q = ((int)hi[e] << 16) | (int)lo[e];
            float val = fmaf((float)q, QI, g_V[vi * 8 + e]);
            float d = val - m;
            float E = __expf(-fabsf(d));
            bool nm = d > 0.0f;
            s = nm ? fmaf(s, E, 1.0f) : (s + E);
            m = nm ? val : m;
        }
    }
    #pragma unroll
    for (int off = 1; off < 64; off <<= 1) {
        float mo = __shfl_xor(m, off, 64), so = __shfl_xor(s, off, 64);
        float m2 = fmaxf(m, mo);
        s = s * __expf(m - m2) + so * __expf(mo - m2);
        m = m2;
    }
    float W = m + logf(s);

    // (2) count-only with tightening
    float tau = TAU;
    int cnt = 0;
    for (int att = 0; att < 5; ++att) {
        cnt = 0;
        float th = W - tau;
        for (int c = 0; c < 16; ++c) {
            int vi = c * 64 + lane;
            u16x8 lo = lop[vi];
            i8x8  hi = hp[vi];
            #pragma unroll
            for (int e = 0; e < 8; ++e) {
                int q = ((int)hi[e] << 16) | (int)lo[e];
                float val = fmaf((float)q, QI, g_V[vi * 8 + e]);
                cnt += (int)__popcll(__ballot(val > th));
            }
        }
        if (cnt <= KMAX) break;
        tau -= 16.0f;
    }
    float th = W - tau;

    // (3) write pass (bounded)
    unsigned long long lanelt = (1ULL << lane) - 1ULL;
    int base = row * KMAX;
    int off0 = 0;
    for (int c = 0; c < 16; ++c) {
        int vi = c * 64 + lane;
        u16x8 lo = lop[vi];
        i8x8  hi = hp[vi];
        #pragma unroll
        for (int e = 0; e < 8; ++e) {
            int q = ((int)hi[e] << 16) | (int)lo[e];
            float val = fmaf((float)q, QI, g_V[vi * 8 + e]);
            bool keep = val > th;
            unsigned long long mask = __ballot(keep);
            int pos = off0 + (int)__popcll(mask & lanelt);
            if (keep && pos < KMAX) {
                int j = vi * 8 + e;
                cidx[base + pos] = (unsigned short)j;
                clo[base + pos] = lo[e];
                chi[base + pos] = hi[e];
                atomicAdd(&g_colcnt[j], 1);
            }
            off0 += (int)__popcll(mask);
        }
    }
    if (lane == 0) g_rowcnt[row] = (cnt < KMAX) ? cnt : KMAX;
}

// 1-block exclusive prefix over g_colcnt -> g_colofs; zero g_colcnt (cursor).
__global__ __launch_bounds__(1024) void col_prefix() {
    __shared__ int ls[1024];
    int t = threadIdx.x;
    int c[8], sum = 0;
    #pragma unroll
    for (int k = 0; k < 8; ++k) { c[k] = g_colcnt[t * 8 + k]; sum += c[k]; }
    ls[t] = sum;
    __syncthreads();
    for (int off = 1; off < 1024; off <<= 1) {
        int add = (t >= off) ? ls[t - off] : 0;
        __syncthreads();
        ls[t] += add;
        __syncthreads();
    }
    int run = (t == 0) ? 0 : ls[t - 1];
    #pragma unroll
    for (int k = 0; k < 8; ++k) {
        g_colofs[t * 8 + k] = run;
        run += c[k];
        g_colcnt[t * 8 + k] = 0;
    }
}

// scatter CSC from CSR (wave per row; atomic slot cursor per column).
// Hardened: j masked, o clamped -- OOB impossible even under corruption.
__global__ __launch_bounds__(512, 2) void build_csc(
        const unsigned short* __restrict__ cidx,
        const unsigned short* __restrict__ clo,
        const signed char* __restrict__ chi,
        unsigned short* __restrict__ ridx,
        unsigned short* __restrict__ rlo,
        signed char* __restrict__ rhi) {
    int t = threadIdx.x;
    int wave = t >> 6, lane = t & 63;
    int row = blockIdx.x * 8 + wave;
    int cnt = g_rowcnt[row];
    cnt = (cnt < KMAX) ? cnt : KMAX;
    int base = row * KMAX;
    for (int e = lane; e < cnt; e += 64) {
        int p = base + e;
        int j = (int)cidx[p] & (B - 1);
        int slot = atomicAdd(&g_colcnt[j], 1);
        int o = g_colofs[j] + slot;
        o = (o < NMAX) ? o : (NMAX - 1);
        o = (o >= 0) ? o : 0;
        ridx[o] = (unsigned short)row;
        rlo[o] = clo[p];
        rhi[o] = chi[p];
    }
}

// sparse row pass: wave per row over CSR -> g_W[row]
__global__ __launch_bounds__(512) void sparse_W(
        const unsigned short* __restrict__ cidx,
        const unsigned short* __restrict__ clo,
        const signed char* __restrict__ chi) {
    int t = threadIdx.x;
    int wave = t >> 6, lane = t & 63;
    int row = blockIdx.x * 8 + wave;
    int cnt = g_rowcnt[row];
    cnt = (cnt < KMAX) ? cnt : KMAX;
    int base = row * KMAX;
    float m = -1e30f;
    for (int e = lane; e < cnt; e += 64) {
        int p = base + e;
        int q = ((int)chi[p] << 16) | (int)clo[p];
        m = fmaxf(m, fmaf((float)q, QI, g_V[(int)cidx[p] & (B - 1)]));
    }
    #pragma unroll
    for (int off = 1; off < 64; off <<= 1)
        m = fmaxf(m, __shfl_xor(m, off, 64));
    float s = 0.0f;
    for (int e = lane; e < cnt; e += 64) {
        int p = base + e;
        int q = ((int)chi[p] << 16) | (int)clo[p];
        s += __expf(fmaf((float)q, QI, g_V[(int)cidx[p] & (B - 1)]) - m);
    }
    #pragma unroll
    for (int off = 1; off < 64; off <<= 1)
        s += __shfl_xor(s, off, 64);
    if (lane == 0) g_W[row] = m + logf(s);
}

// sparse col pass: wave per column over CSC -> V update (no atomics)
__global__ __launch_bounds__(512) void sparse_colV(
        const unsigned short* __restrict__ ridx,
        const unsigned short* __restrict__ rlo,
        const signed char* __restrict__ rhi) {
    int t = threadIdx.x;
    int wave = t >> 6, lane = t & 63;
    int col = blockIdx.x * 8 + wave;
    int cnt = g_colcnt[col];        // cursor == column count after build_csc
    int base = g_colofs[col];
    // harden: base+cnt cannot exceed NMAX (histogram total), but clamp anyway
    if (base < 0) base = 0;
    if (base + cnt > NMAX) cnt = NMAX - base;
    float vj = g_V[col];
    float s = 0.0f;
    for (int e = lane; e < cnt; e += 64) {
        int p = base + e;
        int q = ((int)rhi[p] << 16) | (int)rlo[p];
        s += __expf(fmaf((float)q, QI, vj) - g_W[(int)ridx[p] & (B - 1)]);
    }
    #pragma unroll
    for (int off = 1; off < 64; off <<= 1)
        s += __shfl_xor(s, off, 64);
    if (lane == 0 && cnt > 0)
        g_V[col] = vj - logf(fmaxf(s, 1e-30f));
}

// ---------------- argmax + gather (dense int24 G + final V) ----------------
__global__ __launch_bounds__(256) void argmax_out(const unsigned short* __restrict__ Glo,
                                                  const signed char* __restrict__ Ghi,
                                                  const float* __restrict__ y,
                                                  float* __restrict__ out) {
    int i = blockIdx.x;
    int t = threadIdx.x;
    const u16x8* lo8 = (const u16x8*)(Glo + (size_t)i * B);
    const i8x8*  hi8 = (const i8x8*)(Ghi + (size_t)i * B);
    const f32x4* v4 = (const f32x4*)g_V;
    float best = -INFINITY;
    int bj = 0;
    #pragma unroll
    for (int it = 0; it < 4; ++it) {
        int idx = it * 256 + t;
        u16x8 lo = lo8[idx];
        i8x8  hi = hi8[idx];
        f32x4 va = v4[idx * 2], vb = v4[idx * 2 + 1];
        float vv[8] = {va.x, va.y, va.z, va.w, vb.x, vb.y, vb.z, vb.w};
        #pragma unroll
        for (int k = 0; k < 8; ++k) {
            int q = ((int)hi[k] << 16) | (int)lo[k];
            float val = fmaf((float)q, QI, vv[k]);
            int j = idx * 8 + k;
            if (val > best) { best = val; bj = j; }
        }
    }
    __shared__ float bm[256];
    __shared__ int   bidx[256];
    bm[t] = best; bidx[t] = bj;
    __syncthreads();
    #pragma unroll
    for (int off = 128; off; off >>= 1) {
        if (t < off) {
            float om = bm[t + off]; int oj = bidx[t + off];
            if (om > bm[t] || (om == bm[t] && oj < bidx[t])) { bm[t] = om; bidx[t] = oj; }
        }
        __syncthreads();
    }
    int jstar = bidx[0] & (B - 1);
    out[(size_t)i * C + t] = y[(size_t)jstar * C + t];
}

extern "C" void kernel_launch(void* const* d_in, const int* in_sizes, int n_in,
                              void* d_out, int out_size, void* d_ws, size_t ws_size,
                              hipStream_t stream) {
    const float* x = (const float*)d_in[0];
    const float* y = (const float*)d_in[1];
    float* out = (float*)d_out;
    char* w = (char*)d_ws;
    unsigned short* Glo = (unsigned short*)w;                      // 128 MiB
    signed char*    Ghi = (signed char*)(w + (size_t)B * B * 2);   // +64 MiB
    float* pm = (float*)(w + (size_t)B * B * 3);                   // 16 MiB, dense phase only
    // sparse structures (alias pm region; 10 B/entry * NMAX = 60 MiB):
    unsigned short* cidx = (unsigned short*)(w + (size_t)B * B * 3);
    unsigned short* clo  = (unsigned short*)((char*)cidx + (size_t)NMAX * 2);
    signed char*    chi  = (signed char*)((char*)clo + (size_t)NMAX * 2);
    unsigned short* ridx = (unsigned short*)((char*)chi + (size_t)NMAX);
    unsigned short* rlo  = (unsigned short*)((char*)ridx + (size_t)NMAX * 2);
    signed char*    rhi  = (signed char*)((char*)rlo + (size_t)NMAX * 2);
    // end = 192 + 60 = 252 MiB <= 256 MiB

    init_V<<<B / 4, 256, 0, stream>>>(y);
    gemm_G<<<dim3(B / GT, B / GT), 256, 0, stream>>>(x, y, Glo, Ghi);

    // 8 dense V-updates
    for (int l = 0; l < 8; ++l) {
        fused_iter<<<NCH, 512, 0, stream>>>(Glo, Ghi, pm);
        col_combine<<<B / 32, 256, 0, stream>>>(pm);
    }
    // 4 sparse phases: extract + 23 sparse V-updates each (total 92)
    for (int ph = 0; ph < 4; ++ph) {
        sreset<<<B / 256, 256, 0, stream>>>();
        extract<<<B / 8, 512, 0, stream>>>(Glo, Ghi, cidx, clo, chi);
        col_prefix<<<1, 1024, 0, stream>>>();
        build_csc<<<B / 8, 512, 0, stream>>>(cidx, clo, chi, ridx, rlo, rhi);
        for (int l = 0; l < 23; ++l) {
            sparse_W<<<B / 8, 512, 0, stream>>>(cidx, clo, chi);
            sparse_colV<<<B / 8, 512, 0, stream>>>(ridx, rlo, rhi);
        }
    }
    argmax_out<<<B, 256, 0, stream>>>(Glo, Ghi, y, out);
}

// Round 14
// 5016.795 us; speedup vs baseline: 1.4051x; 1.4051x over previous
//
#include <hip/hip_runtime.h>
#include <math.h>

// Sinkhorn OT layer, B=8192, C=256, L=100, LAMBD=1.
//
// U = log_u - ||x_i||^2, V = log_v - ||y_j||^2, G[i][j] = 2*dot(x_i,y_j):
//   U[i] = -LSE_j(G[i][j] + V[j]),  V[j] = -LSE_i(G[i][j] + U[i])
// init V[j] = -||y_j||^2. Final: out[i] = y[argmax_j(G[i][j]+V[j])].
//
// History: R6 int24 G 7498 | R13 register-resident fused dense iter 4875
// (~43 us/iter, ~95% of achievable; FETCH shows ~50% of G served by L3) |
// R14/R16/R17/R18 sparse: numerics validated 4x (absmax 0) but
// DISPATCH-GRANULARITY-BOUND (184 ~10us dispatches x ~20us overhead,
// occupancy 2.9%) -> abandoned | R15 bitwise-cycle exit: never fires.
// R19 = R13 restored + gemm retune:
//  - gemm 128x64 tile, acc 8x4 (128 FMA per 12 LDS-b128, was 64 per 8),
//    a-rows interleaved ty+16*ii -> the 4 ty-lanes/wave hit 4 distinct
//    banks (36-float spacing) = conflict-free; plain launch_bounds(256)
//    (R12's spill was the (,4) VGPR cap; ~110 live regs fits).
//  - nontemporal hints on pm traffic (preserve L3 capacity for G).
//
// Kept: int24 G (q=2^-15, err 1.5e-5), register-resident fusion (thread
// owns 16 cols, val[] survives block row-reduce, 1 exp/element, G read
// once/iter), one barrier/window, combine clamp, smallest-index argmax.

#define B 8192
#define C 256
#define LITERS 100
#define RPB 16                     // rows per fused block
#define NCH (B / RPB)              // 512 chunks

#define QS 65536.0f                // (2*acc) * 32768 == acc * 65536
#define QI 3.0517578125e-5f        // 2^-15

typedef float f32x4 __attribute__((ext_vector_type(4)));
typedef unsigned short u16x8 __attribute__((ext_vector_type(8)));
typedef signed char i8x16 __attribute__((ext_vector_type(16)));
typedef signed char i8x8 __attribute__((ext_vector_type(8)));

__device__ __align__(16) float g_V[B];

// ---------------- init: V[j] = -||y_j||^2 ----------------
__global__ __launch_bounds__(256) void init_V(const float* __restrict__ y) {
    int wave = threadIdx.x >> 6;
    int lane = threadIdx.x & 63;
    int row = blockIdx.x * 4 + wave;
    const f32x4* yr = (const f32x4*)(y + (size_t)row * C);
    f32x4 v = yr[lane];
    float s = v.x * v.x + v.y * v.y + v.z * v.z + v.w * v.w;
    #pragma unroll
    for (int off = 32; off; off >>= 1) s += __shfl_down(s, off, 64);
    if (lane == 0) g_V[row] = -s;
}

// ---------------- GEMM: G = 2 * x @ y^T, quantized to int24 ----------------
// 128x64 tile, 256 threads, acc 8x4. A-rows for thread = ty + 16*ii
// (ii<8): within a wave ty spans 4 values -> LDS addrs 36 floats apart
// -> 4 distinct banks, conflict-free. B-rows tx+16*jj: spacing 36*1 -> 2-way
// at worst (free).
#define GM 128
#define GN 64
#define GK 32
#define LST (GK + 4)   // 36 floats

__global__ __launch_bounds__(256) void gemm_G(const float* __restrict__ x,
                                              const float* __restrict__ y,
                                              unsigned short* __restrict__ Glo,
                                              signed char* __restrict__ Ghi) {
    __shared__ float As[GM][LST];   // 128 x 36 (18 KiB)
    __shared__ float Bs[GN][LST];   // 64 x 36  (9 KiB)
    int bi = blockIdx.y * GM;
    int bj = blockIdx.x * GN;
    int t = threadIdx.x;
    int tx = t & 15, ty = t >> 4;          // ty 0..15
    float acc[8][4] = {};
    for (int kk = 0; kk < C; kk += GK) {
        #pragma unroll
        for (int l = 0; l < 4; ++l) {      // stage A: 4 float4/thread
            int fid = t + l * 256;         // 0..1023
            int r = fid >> 3;              // 0..127
            int c4 = fid & 7;              // 0..7
            *(f32x4*)&As[r][c4 * 4] =
                *(const f32x4*)(x + (size_t)(bi + r) * C + kk + c4 * 4);
        }
        #pragma unroll
        for (int l = 0; l < 2; ++l) {      // stage B: 2 float4/thread
            int fid = t + l * 256;         // 0..511
            int r = fid >> 3;              // 0..63
            int c4 = fid & 7;
            *(f32x4*)&Bs[r][c4 * 4] =
                *(const f32x4*)(y + (size_t)(bj + r) * C + kk + c4 * 4);
        }
        __syncthreads();
        #pragma unroll
        for (int k4 = 0; k4 < GK / 4; ++k4) {
            f32x4 a[8], b[4];
            #pragma unroll
            for (int ii = 0; ii < 8; ++ii)
                a[ii] = *(const f32x4*)&As[ty + 16 * ii][k4 * 4];
            #pragma unroll
            for (int jj = 0; jj < 4; ++jj)
                b[jj] = *(const f32x4*)&Bs[tx + 16 * jj][k4 * 4];
            #pragma unroll
            for (int ii = 0; ii < 8; ++ii)
                #pragma unroll
                for (int jj = 0; jj < 4; ++jj) {
                    acc[ii][jj] = fmaf(a[ii].x, b[jj].x, acc[ii][jj]);
                    acc[ii][jj] = fmaf(a[ii].y, b[jj].y, acc[ii][jj]);
                    acc[ii][jj] = fmaf(a[ii].z, b[jj].z, acc[ii][jj]);
                    acc[ii][jj] = fmaf(a[ii].w, b[jj].w, acc[ii][jj]);
                }
        }
        __syncthreads();
    }
    #pragma unroll
    for (int ii = 0; ii < 8; ++ii) {
        int gi = bi + ty + 16 * ii;
        #pragma unroll
        for (int jj = 0; jj < 4; ++jj) {
            size_t idx = (size_t)gi * B + bj + tx + 16 * jj;
            float gs = acc[ii][jj] * QS;                       // G * 2^15
            gs = fminf(fmaxf(gs, -8388607.0f), 8388607.0f);    // int24 clamp
            int v = __float2int_rn(gs);
            Glo[idx] = (unsigned short)(v & 0xFFFF);
            Ghi[idx] = (signed char)(v >> 16);
        }
    }
}

// ---------------- fused row+col pass (R13, 1 barrier/window) ----------------
// Block = 512 threads (8 waves), owns rows [chunk*16, chunk*16+16).
// Thread t owns cols 16t..16t+15 for every row. Window = 2 rows.
__global__ __launch_bounds__(512, 4) void fused_iter(
        const unsigned short* __restrict__ Glo,
        const signed char* __restrict__ Ghi,
        float* __restrict__ pm) {
    __shared__ float wm[2][2][8];   // [buf][row][wave]
    __shared__ float ws[2][2][8];
    int t = threadIdx.x;
    int chunk = blockIdx.x;
    int i0 = chunk * RPB;
    int wave = t >> 6, lane = t & 63;

    float vreg[16];
    #pragma unroll
    for (int q = 0; q < 4; ++q) {
        f32x4 v = *(const f32x4*)&g_V[16 * t + 4 * q];
        vreg[4 * q + 0] = v.x; vreg[4 * q + 1] = v.y;
        vreg[4 * q + 2] = v.z; vreg[4 * q + 3] = v.w;
    }
    float cs[16];
    #pragma unroll
    for (int k = 0; k < 16; ++k) cs[k] = 0.0f;

    for (int w = 0; w < RPB / 2; ++w) {
        int buf = w & 1;
        int ra = i0 + 2 * w;
        int rb = ra + 1;
        float val0[16], val1[16];
        {
            const u16x8* lop = (const u16x8*)(Glo + (size_t)ra * B);
            const i8x16* hp  = (const i8x16*)(Ghi + (size_t)ra * B);
            u16x8 a0 = lop[2 * t], a1 = lop[2 * t + 1];
            i8x16 h = hp[t];
            #pragma unroll
            for (int e = 0; e < 8; ++e) {
                int q0 = ((int)h[e] << 16) | (int)a0[e];
                val0[e] = fmaf((float)q0, QI, vreg[e]);
                int q1 = ((int)h[8 + e] << 16) | (int)a1[e];
                val0[8 + e] = fmaf((float)q1, QI, vreg[8 + e]);
            }
        }
        {
            const u16x8* lop = (const u16x8*)(Glo + (size_t)rb * B);
            const i8x16* hp  = (const i8x16*)(Ghi + (size_t)rb * B);
            u16x8 a0 = lop[2 * t], a1 = lop[2 * t + 1];
            i8x16 h = hp[t];
            #pragma unroll
            for (int e = 0; e < 8; ++e) {
                int q0 = ((int)h[e] << 16) | (int)a0[e];
                val1[e] = fmaf((float)q0, QI, vreg[e]);
                int q1 = ((int)h[8 + e] << 16) | (int)a1[e];
                val1[8 + e] = fmaf((float)q1, QI, vreg[8 + e]);
            }
        }
        float M0 = val0[0], M1 = val1[0];
        #pragma unroll
        for (int k = 1; k < 16; ++k) {
            M0 = fmaxf(M0, val0[k]);
            M1 = fmaxf(M1, val1[k]);
        }
        #pragma unroll
        for (int off = 1; off < 64; off <<= 1) {
            M0 = fmaxf(M0, __shfl_xor(M0, off, 64));
            M1 = fmaxf(M1, __shfl_xor(M1, off, 64));
        }
        float s0 = 0.0f, s1 = 0.0f;
        #pragma unroll
        for (int k = 0; k < 16; ++k) {
            val0[k] = __expf(val0[k] - M0); s0 += val0[k];
            val1[k] = __expf(val1[k] - M1); s1 += val1[k];
        }
        #pragma unroll
        for (int off = 1; off < 64; off <<= 1) {
            s0 += __shfl_xor(s0, off, 64);
            s1 += __shfl_xor(s1, off, 64);
        }
        if (lane == 0) {
            wm[buf][0][wave] = M0; ws[buf][0][wave] = s0;
            wm[buf][1][wave] = M1; ws[buf][1][wave] = s1;
        }
        __syncthreads();
        float gM0 = wm[buf][0][0], gM1 = wm[buf][1][0];
        #pragma unroll
        for (int k = 1; k < 8; ++k) {
            gM0 = fmaxf(gM0, wm[buf][0][k]);
            gM1 = fmaxf(gM1, wm[buf][1][k]);
        }
        float gS0 = 0.0f, gS1 = 0.0f;
        #pragma unroll
        for (int k = 0; k < 8; ++k) {
            gS0 += ws[buf][0][k] * __expf(wm[buf][0][k] - gM0);
            gS1 += ws[buf][1][k] * __expf(wm[buf][1][k] - gM1);
        }
        float f0 = __expf(M0 - gM0) / gS0;
        float f1 = __expf(M1 - gM1) / gS1;
        #pragma unroll
        for (int k = 0; k < 16; ++k) {
            cs[k] = fmaf(val0[k], f0, cs[k]);
            cs[k] = fmaf(val1[k], f1, cs[k]);
        }
    }
    #pragma unroll
    for (int q = 0; q < 4; ++q) {
        f32x4 o = {cs[4 * q + 0], cs[4 * q + 1], cs[4 * q + 2], cs[4 * q + 3]};
        __builtin_nontemporal_store(o, (f32x4*)&pm[(size_t)chunk * B + 16 * t + 4 * q]);
    }
}

// ---------------- combine: V[j] -= log(sum of 512 chunk partials) ----------------
__global__ __launch_bounds__(256) void col_combine(const float* __restrict__ pm) {
    int t = threadIdx.x;
    int pl = t & 31;
    int g = t >> 5;               // 0..7
    int j = blockIdx.x * 32 + pl;
    float s = 0.0f;
    #pragma unroll 8
    for (int c = g * 64; c < g * 64 + 64; ++c)
        s += __builtin_nontemporal_load(&pm[(size_t)c * B + j]);
    __shared__ float ls[8][32];
    ls[g][pl] = s;
    __syncthreads();
    if (t < 32) {
        float s0 = ls[0][t];
        #pragma unroll
        for (int gg = 1; gg < 8; ++gg) s0 += ls[gg][t];
        int jj = blockIdx.x * 32 + t;
        // clamp: all-underflow columns get a bounded push (self-correcting)
        g_V[jj] -= logf(fmaxf(s0, 1e-30f));
    }
}

// ---------------- argmax + gather: out[i] = y[argmax_j(G[i][j]+V[j])] ----------------
__global__ __launch_bounds__(256) void argmax_out(const unsigned short* __restrict__ Glo,
                                                  const signed char* __restrict__ Ghi,
                                                  const float* __restrict__ y,
                                                  float* __restrict__ out) {
    int i = blockIdx.x;
    int t = threadIdx.x;
    const u16x8* lo8 = (const u16x8*)(Glo + (size_t)i * B);
    const i8x8*  hi8 = (const i8x8*)(Ghi + (size_t)i * B);
    const f32x4* v4 = (const f32x4*)g_V;
    float best = -INFINITY;
    int bj = 0;                              // safe init (never OOB)
    #pragma unroll
    for (int it = 0; it < 4; ++it) {
        int idx = it * 256 + t;
        u16x8 lo = lo8[idx];
        i8x8  hi = hi8[idx];
        f32x4 va = v4[idx * 2], vb = v4[idx * 2 + 1];
        float vv[8] = {va.x, va.y, va.z, va.w, vb.x, vb.y, vb.z, vb.w};
        #pragma unroll
        for (int k = 0; k < 8; ++k) {
            int q = ((int)hi[k] << 16) | (int)lo[k];
            float val = fmaf((float)q, QI, vv[k]);
            int j = idx * 8 + k;
            if (val > best) { best = val; bj = j; }
        }
    }
    __shared__ float bm[256];
    __shared__ int   bidx[256];
    bm[t] = best; bidx[t] = bj;
    __syncthreads();
    #pragma unroll
    for (int off = 128; off; off >>= 1) {
        if (t < off) {
            float om = bm[t + off]; int oj = bidx[t + off];
            if (om > bm[t] || (om == bm[t] && oj < bidx[t])) { bm[t] = om; bidx[t] = oj; }
        }
        __syncthreads();
    }
    int jstar = bidx[0] & (B - 1);
    out[(size_t)i * C + t] = y[(size_t)jstar * C + t];
}

extern "C" void kernel_launch(void* const* d_in, const int* in_sizes, int n_in,
                              void* d_out, int out_size, void* d_ws, size_t ws_size,
                              hipStream_t stream) {
    const float* x = (const float*)d_in[0];
    const float* y = (const float*)d_in[1];
    float* out = (float*)d_out;
    unsigned short* Glo = (unsigned short*)d_ws;                           // 128 MiB
    signed char*    Ghi = (signed char*)((char*)d_ws + (size_t)B * B * 2); // +64 MiB
    float* pm = (float*)((char*)d_ws + (size_t)B * B * 3);                 // +16 MiB

    init_V<<<B / 4, 256, 0, stream>>>(y);
    gemm_G<<<dim3(B / GN, B / GM), 256, 0, stream>>>(x, y, Glo, Ghi);
    for (int l = 0; l < LITERS; ++l) {
        fused_iter<<<NCH, 512, 0, stream>>>(Glo, Ghi, pm);
        col_combine<<<B / 32, 256, 0, stream>>>(pm);
    }
    argmax_out<<<B, 256, 0, stream>>>(Glo, Ghi, y, out);
}

// Round 15
// 4812.743 us; speedup vs baseline: 1.4647x; 1.0424x over previous
//
#include <hip/hip_runtime.h>
#include <math.h>

// Sinkhorn OT layer, B=8192, C=256, L=100, LAMBD=1.
//
// U = log_u - ||x_i||^2, V = log_v - ||y_j||^2, G[i][j] = 2*dot(x_i,y_j):
//   U[i] = -LSE_j(G[i][j] + V[j]),  V[j] = -LSE_i(G[i][j] + U[i])
// init V[j] = -||y_j||^2. Final: out[i] = y[argmax_j(G[i][j]+V[j])].
//
// History: R6 int24 G 7498 | R13 fused dense iter 4875 (42.9 us/iter) |
// sparse (R14/16/17/18): numerics valid, dispatch-granularity-bound ->
// abandoned | R15 cycle-exit: never fires | R19: gemm retile WIN
// (545->495) but nontemporal pm hints LOST 190 us (pm read was L2/L3-hot;
// nontemporal bypassed the cache that was helping) -> 5017.
// R20 = R19 gemm + R13 pm paths (plain loads/stores). Best measured
// variant of each component.
//
// Kept: int24 G (q=2^-15, err 1.5e-5 ~ fp32 noise class), register-
// resident fusion (thread owns 16 cols, val[] survives block row-reduce
// in regs, 1 exp/element, G read once/iter), one barrier/window,
// combine clamp, smallest-index argmax tie-break.

#define B 8192
#define C 256
#define LITERS 100
#define RPB 16                     // rows per fused block
#define NCH (B / RPB)              // 512 chunks

#define QS 65536.0f                // (2*acc) * 32768 == acc * 65536
#define QI 3.0517578125e-5f        // 2^-15

typedef float f32x4 __attribute__((ext_vector_type(4)));
typedef unsigned short u16x8 __attribute__((ext_vector_type(8)));
typedef signed char i8x16 __attribute__((ext_vector_type(16)));
typedef signed char i8x8 __attribute__((ext_vector_type(8)));

__device__ __align__(16) float g_V[B];

// ---------------- init: V[j] = -||y_j||^2 ----------------
__global__ __launch_bounds__(256) void init_V(const float* __restrict__ y) {
    int wave = threadIdx.x >> 6;
    int lane = threadIdx.x & 63;
    int row = blockIdx.x * 4 + wave;
    const f32x4* yr = (const f32x4*)(y + (size_t)row * C);
    f32x4 v = yr[lane];
    float s = v.x * v.x + v.y * v.y + v.z * v.z + v.w * v.w;
    #pragma unroll
    for (int off = 32; off; off >>= 1) s += __shfl_down(s, off, 64);
    if (lane == 0) g_V[row] = -s;
}

// ---------------- GEMM: G = 2 * x @ y^T, quantized to int24 (R19 tile) ----------------
// 128x64 tile, 256 threads, acc 8x4 (128 FMA per 12 LDS-b128). A-rows
// ty+16*ii: 4 ty-lanes/wave -> 36-float spacing -> 4 distinct banks.
#define GM 128
#define GN 64
#define GK 32
#define LST (GK + 4)   // 36 floats

__global__ __launch_bounds__(256) void gemm_G(const float* __restrict__ x,
                                              const float* __restrict__ y,
                                              unsigned short* __restrict__ Glo,
                                              signed char* __restrict__ Ghi) {
    __shared__ float As[GM][LST];   // 128 x 36 (18 KiB)
    __shared__ float Bs[GN][LST];   // 64 x 36  (9 KiB)
    int bi = blockIdx.y * GM;
    int bj = blockIdx.x * GN;
    int t = threadIdx.x;
    int tx = t & 15, ty = t >> 4;          // ty 0..15
    float acc[8][4] = {};
    for (int kk = 0; kk < C; kk += GK) {
        #pragma unroll
        for (int l = 0; l < 4; ++l) {      // stage A: 4 float4/thread
            int fid = t + l * 256;         // 0..1023
            int r = fid >> 3;              // 0..127
            int c4 = fid & 7;              // 0..7
            *(f32x4*)&As[r][c4 * 4] =
                *(const f32x4*)(x + (size_t)(bi + r) * C + kk + c4 * 4);
        }
        #pragma unroll
        for (int l = 0; l < 2; ++l) {      // stage B: 2 float4/thread
            int fid = t + l * 256;         // 0..511
            int r = fid >> 3;              // 0..63
            int c4 = fid & 7;
            *(f32x4*)&Bs[r][c4 * 4] =
                *(const f32x4*)(y + (size_t)(bj + r) * C + kk + c4 * 4);
        }
        __syncthreads();
        #pragma unroll
        for (int k4 = 0; k4 < GK / 4; ++k4) {
            f32x4 a[8], b[4];
            #pragma unroll
            for (int ii = 0; ii < 8; ++ii)
                a[ii] = *(const f32x4*)&As[ty + 16 * ii][k4 * 4];
            #pragma unroll
            for (int jj = 0; jj < 4; ++jj)
                b[jj] = *(const f32x4*)&Bs[tx + 16 * jj][k4 * 4];
            #pragma unroll
            for (int ii = 0; ii < 8; ++ii)
                #pragma unroll
                for (int jj = 0; jj < 4; ++jj) {
                    acc[ii][jj] = fmaf(a[ii].x, b[jj].x, acc[ii][jj]);
                    acc[ii][jj] = fmaf(a[ii].y, b[jj].y, acc[ii][jj]);
                    acc[ii][jj] = fmaf(a[ii].z, b[jj].z, acc[ii][jj]);
                    acc[ii][jj] = fmaf(a[ii].w, b[jj].w, acc[ii][jj]);
                }
        }
        __syncthreads();
    }
    #pragma unroll
    for (int ii = 0; ii < 8; ++ii) {
        int gi = bi + ty + 16 * ii;
        #pragma unroll
        for (int jj = 0; jj < 4; ++jj) {
            size_t idx = (size_t)gi * B + bj + tx + 16 * jj;
            float gs = acc[ii][jj] * QS;                       // G * 2^15
            gs = fminf(fmaxf(gs, -8388607.0f), 8388607.0f);    // int24 clamp
            int v = __float2int_rn(gs);
            Glo[idx] = (unsigned short)(v & 0xFFFF);
            Ghi[idx] = (signed char)(v >> 16);
        }
    }
}

// ---------------- fused row+col pass (R13, 1 barrier/window) ----------------
// Block = 512 threads (8 waves), owns rows [chunk*16, chunk*16+16).
// Thread t owns cols 16t..16t+15 for every row. Window = 2 rows.
__global__ __launch_bounds__(512, 4) void fused_iter(
        const unsigned short* __restrict__ Glo,
        const signed char* __restrict__ Ghi,
        float* __restrict__ pm) {
    __shared__ float wm[2][2][8];   // [buf][row][wave]
    __shared__ float ws[2][2][8];
    int t = threadIdx.x;
    int chunk = blockIdx.x;
    int i0 = chunk * RPB;
    int wave = t >> 6, lane = t & 63;

    float vreg[16];
    #pragma unroll
    for (int q = 0; q < 4; ++q) {
        f32x4 v = *(const f32x4*)&g_V[16 * t + 4 * q];
        vreg[4 * q + 0] = v.x; vreg[4 * q + 1] = v.y;
        vreg[4 * q + 2] = v.z; vreg[4 * q + 3] = v.w;
    }
    float cs[16];
    #pragma unroll
    for (int k = 0; k < 16; ++k) cs[k] = 0.0f;

    for (int w = 0; w < RPB / 2; ++w) {
        int buf = w & 1;
        int ra = i0 + 2 * w;
        int rb = ra + 1;
        float val0[16], val1[16];
        {
            const u16x8* lop = (const u16x8*)(Glo + (size_t)ra * B);
            const i8x16* hp  = (const i8x16*)(Ghi + (size_t)ra * B);
            u16x8 a0 = lop[2 * t], a1 = lop[2 * t + 1];
            i8x16 h = hp[t];
            #pragma unroll
            for (int e = 0; e < 8; ++e) {
                int q0 = ((int)h[e] << 16) | (int)a0[e];
                val0[e] = fmaf((float)q0, QI, vreg[e]);
                int q1 = ((int)h[8 + e] << 16) | (int)a1[e];
                val0[8 + e] = fmaf((float)q1, QI, vreg[8 + e]);
            }
        }
        {
            const u16x8* lop = (const u16x8*)(Glo + (size_t)rb * B);
            const i8x16* hp  = (const i8x16*)(Ghi + (size_t)rb * B);
            u16x8 a0 = lop[2 * t], a1 = lop[2 * t + 1];
            i8x16 h = hp[t];
            #pragma unroll
            for (int e = 0; e < 8; ++e) {
                int q0 = ((int)h[e] << 16) | (int)a0[e];
                val1[e] = fmaf((float)q0, QI, vreg[e]);
                int q1 = ((int)h[8 + e] << 16) | (int)a1[e];
                val1[8 + e] = fmaf((float)q1, QI, vreg[8 + e]);
            }
        }
        float M0 = val0[0], M1 = val1[0];
        #pragma unroll
        for (int k = 1; k < 16; ++k) {
            M0 = fmaxf(M0, val0[k]);
            M1 = fmaxf(M1, val1[k]);
        }
        #pragma unroll
        for (int off = 1; off < 64; off <<= 1) {
            M0 = fmaxf(M0, __shfl_xor(M0, off, 64));
            M1 = fmaxf(M1, __shfl_xor(M1, off, 64));
        }
        float s0 = 0.0f, s1 = 0.0f;
        #pragma unroll
        for (int k = 0; k < 16; ++k) {
            val0[k] = __expf(val0[k] - M0); s0 += val0[k];
            val1[k] = __expf(val1[k] - M1); s1 += val1[k];
        }
        #pragma unroll
        for (int off = 1; off < 64; off <<= 1) {
            s0 += __shfl_xor(s0, off, 64);
            s1 += __shfl_xor(s1, off, 64);
        }
        if (lane == 0) {
            wm[buf][0][wave] = M0; ws[buf][0][wave] = s0;
            wm[buf][1][wave] = M1; ws[buf][1][wave] = s1;
        }
        __syncthreads();
        float gM0 = wm[buf][0][0], gM1 = wm[buf][1][0];
        #pragma unroll
        for (int k = 1; k < 8; ++k) {
            gM0 = fmaxf(gM0, wm[buf][0][k]);
            gM1 = fmaxf(gM1, wm[buf][1][k]);
        }
        float gS0 = 0.0f, gS1 = 0.0f;
        #pragma unroll
        for (int k = 0; k < 8; ++k) {
            gS0 += ws[buf][0][k] * __expf(wm[buf][0][k] - gM0);
            gS1 += ws[buf][1][k] * __expf(wm[buf][1][k] - gM1);
        }
        float f0 = __expf(M0 - gM0) / gS0;
        float f1 = __expf(M1 - gM1) / gS1;
        #pragma unroll
        for (int k = 0; k < 16; ++k) {
            cs[k] = fmaf(val0[k], f0, cs[k]);
            cs[k] = fmaf(val1[k], f1, cs[k]);
        }
    }
    #pragma unroll
    for (int q = 0; q < 4; ++q) {
        f32x4 o = {cs[4 * q + 0], cs[4 * q + 1], cs[4 * q + 2], cs[4 * q + 3]};
        *(f32x4*)&pm[(size_t)chunk * B + 16 * t + 4 * q] = o;
    }
}

// ---------------- combine: V[j] -= log(sum of 512 chunk partials) ----------------
__global__ __launch_bounds__(256) void col_combine(const float* __restrict__ pm) {
    int t = threadIdx.x;
    int pl = t & 31;
    int g = t >> 5;               // 0..7
    int j = blockIdx.x * 32 + pl;
    float s = 0.0f;
    #pragma unroll 8
    for (int c = g * 64; c < g * 64 + 64; ++c)
        s += pm[(size_t)c * B + j];
    __shared__ float ls[8][32];
    ls[g][pl] = s;
    __syncthreads();
    if (t < 32) {
        float s0 = ls[0][t];
        #pragma unroll
        for (int gg = 1; gg < 8; ++gg) s0 += ls[gg][t];
        int jj = blockIdx.x * 32 + t;
        // clamp: all-underflow columns get a bounded push (self-correcting)
        g_V[jj] -= logf(fmaxf(s0, 1e-30f));
    }
}

// ---------------- argmax + gather: out[i] = y[argmax_j(G[i][j]+V[j])] ----------------
__global__ __launch_bounds__(256) void argmax_out(const unsigned short* __restrict__ Glo,
                                                  const signed char* __restrict__ Ghi,
                                                  const float* __restrict__ y,
                                                  float* __restrict__ out) {
    int i = blockIdx.x;
    int t = threadIdx.x;
    const u16x8* lo8 = (const u16x8*)(Glo + (size_t)i * B);
    const i8x8*  hi8 = (const i8x8*)(Ghi + (size_t)i * B);
    const f32x4* v4 = (const f32x4*)g_V;
    float best = -INFINITY;
    int bj = 0;                              // safe init (never OOB)
    #pragma unroll
    for (int it = 0; it < 4; ++it) {
        int idx = it * 256 + t;
        u16x8 lo = lo8[idx];
        i8x8  hi = hi8[idx];
        f32x4 va = v4[idx * 2], vb = v4[idx * 2 + 1];
        float vv[8] = {va.x, va.y, va.z, va.w, vb.x, vb.y, vb.z, vb.w};
        #pragma unroll
        for (int k = 0; k < 8; ++k) {
            int q = ((int)hi[k] << 16) | (int)lo[k];
            float val = fmaf((float)q, QI, vv[k]);
            int j = idx * 8 + k;
            if (val > best) { best = val; bj = j; }
        }
    }
    __shared__ float bm[256];
    __shared__ int   bidx[256];
    bm[t] = best; bidx[t] = bj;
    __syncthreads();
    #pragma unroll
    for (int off = 128; off; off >>= 1) {
        if (t < off) {
            float om = bm[t + off]; int oj = bidx[t + off];
            if (om > bm[t] || (om == bm[t] && oj < bidx[t])) { bm[t] = om; bidx[t] = oj; }
        }
        __syncthreads();
    }
    int jstar = bidx[0] & (B - 1);
    out[(size_t)i * C + t] = y[(size_t)jstar * C + t];
}

extern "C" void kernel_launch(void* const* d_in, const int* in_sizes, int n_in,
                              void* d_out, int out_size, void* d_ws, size_t ws_size,
                              hipStream_t stream) {
    const float* x = (const float*)d_in[0];
    const float* y = (const float*)d_in[1];
    float* out = (float*)d_out;
    unsigned short* Glo = (unsigned short*)d_ws;                           // 128 MiB
    signed char*    Ghi = (signed char*)((char*)d_ws + (size_t)B * B * 2); // +64 MiB
    float* pm = (float*)((char*)d_ws + (size_t)B * B * 3);                 // +16 MiB

    init_V<<<B / 4, 256, 0, stream>>>(y);
    gemm_G<<<dim3(B / GN, B / GM), 256, 0, stream>>>(x, y, Glo, Ghi);
    for (int l = 0; l < LITERS; ++l) {
        fused_iter<<<NCH, 512, 0, stream>>>(Glo, Ghi, pm);
        col_combine<<<B / 32, 256, 0, stream>>>(pm);
    }
    argmax_out<<<B, 256, 0, stream>>>(Glo, Ghi, y, out);
}